// Round 8
// baseline (187.314 us; speedup 1.0000x reference)
//
#include <hip/hip_runtime.h>
#include <cstdint>

#define N_VIS   8192
#define N_ASSOC 4096
#define N_MOTOR 1024
#define IN_DIM  4096
#define T_STEPS 16

// ---------------- encoder + visual LIF: 1 row/wave, double-buffered x tile, 1 barrier/chunk ----
__global__ __launch_bounds__(512, 8) void encoder_kernel(
        const float* __restrict__ x, const float* __restrict__ noise,
        const float* __restrict__ W, const float* __restrict__ b,
        unsigned* __restrict__ vmask) {
    __shared__ float4 xs[2][16 * 64];            // two 16 KB tiles: [t][64 float4] of a 256-col chunk
    const int tid = threadIdx.x;
    const int wave = tid >> 6, lane = tid & 63;
    const int r = blockIdx.x * 8 + wave;         // one visual row per wave
    const float4* Wr = (const float4*)(W + (size_t)r * IN_DIM);

    float a[T_STEPS];
#pragma unroll
    for (int t = 0; t < T_STEPS; ++t) a[t] = 0.f;

    auto stage = [&](int c, int buf) {
#pragma unroll
        for (int p = 0; p < 2; ++p) {
            int f = tid + p * 512;               // 1024 float4s staged by 512 threads
            int t = f >> 6, c4 = f & 63;
            xs[buf][f] = ((const float4*)(x + (size_t)t * IN_DIM + c * 256))[c4];
        }
    };
    stage(0, 0);
    float4 wv = Wr[lane];                        // W chunk 0
    __syncthreads();

#pragma unroll 1
    for (int c = 0; c < 16; ++c) {
        const int cb = c & 1;
        if (c < 15) stage(c + 1, cb ^ 1);        // issue next-tile loads first
        float4 nwv = wv;
        if (c < 15) nwv = Wr[(c + 1) * 64 + lane];  // prefetch next W chunk
#pragma unroll
        for (int t = 0; t < T_STEPS; ++t) {
            float4 xv = xs[cb][t * 64 + lane];
            a[t] += wv.x*xv.x + wv.y*xv.y + wv.z*xv.z + wv.w*xv.w;   // same expr/order as R7
        }
        __syncthreads();                         // single barrier per chunk
        wv = nwv;
    }

#pragma unroll
    for (int t = 0; t < T_STEPS; ++t) {
        float v = a[t];
        for (int o = 32; o; o >>= 1) v += __shfl_xor(v, o, 64);
        a[t] = v;
    }
    if (lane == 0) {
        float bb = b[r];
        float v = 0.f;
        unsigned msk = 0;
#pragma unroll
        for (int t = 0; t < T_STEPS; ++t) {
            float logit = a[t] + bb;
            float rate = 1.0f / (1.0f + expf(-logit));
            float u = noise[t * N_VIS + r];
            float ins = (u < rate * 0.3f) ? 1.0f : 0.0f;
            v = v * 0.95f + ins;
            if (v > 1.0f) { msk |= (1u << t); v = 0.f; }
        }
        vmask[r] = msk;
    }
}

// ---------------- K table: K[t][r] = sum_{s=r..t-1} g_s * d_s*0.1*0.01*C[s][r] ----------------
__global__ void ktab_kernel(const float* __restrict__ dop, float* __restrict__ K) {
    __shared__ float C[256];      // C[s*16+r]
    __shared__ float sd[16];
    __shared__ unsigned sg[16];
    const int p = threadIdx.x;    // 256 threads: p = s*16 + r  (then t*16 + r)
    if (p < 16) {
        float d = dop[p];
        sd[p] = d;
        sg[p] = (fabsf(d) > 0.1f) ? 1u : 0u;
    }
    __syncthreads();
    {
        const int s = p >> 4, r = p & 15;
        float c = 0.f;
        if (s >= r) {
            c = 1.f;                              // C[r][r] = 1
            for (int u = r; u < s; ++u) {         // same op order as sequential build
                if (sg[u]) c *= 0.5f;
                c *= 0.998f;
            }
        }
        C[p] = c;
    }
    __syncthreads();
    {
        const int t = p >> 4, r = p & 15;
        float kk = 0.f;
        for (int s = r; s < t; ++s)
            if (sg[s]) kk += ((sd[s] * 0.1f) * 0.01f) * C[s * 16 + r];
        K[p] = kk;
    }
}

// ---------------- OVL[r][t] = popcount over mask words of bit_r & bit_t ----------------
__global__ void ovl_kernel(const unsigned* __restrict__ mask, int words_per_block,
                           int* __restrict__ ovl) {
    const int p = threadIdx.x;            // 256 threads: p = r*16 + t
    const int r = p >> 4, t = p & 15;
    const unsigned* w = mask + blockIdx.x * words_per_block;
    int c = 0;
    for (int i = 0; i < words_per_block; ++i)
        c += (int)((w[i] >> r) & (w[i] >> t) & 1u);
    atomicAdd(&ovl[p], c);
}

// ---------------- base pass: base[j][t] = sum_i W0[j,i]*v_t(i); ONE row per 256-thr block ----
// NC = float4 chunks per thread (row length = NC * 1024 floats). VA: NC=8, AM: NC=4.
template<int NC>
__global__ __launch_bounds__(256, 8) void base_kernel(
        const float* __restrict__ W0, const unsigned* __restrict__ colmask,
        float* __restrict__ base) {
    const int j = blockIdx.x;
    const int tid = threadIdx.x;
    const int lane = tid & 63, wv = tid >> 6;      // 4 waves
    __shared__ float sred[4][T_STEPS];

    const float4* Wr = (const float4*)(W0 + (size_t)j * (NC * 1024));
    const uint4*  cm = (const uint4*)colmask;

    float acc[T_STEPS];
#pragma unroll
    for (int t = 0; t < T_STEPS; ++t) acc[t] = 0.f;

#pragma unroll
    for (int k = 0; k < NC; ++k) {
        float4 q = Wr[tid + k * 256];
        uint4  m = cm [tid + k * 256];
        unsigned plo = m.x | (m.y << 16);
        unsigned phi = m.z | (m.w << 16);
#pragma unroll
        for (int t = 0; t < T_STEPS; ++t) {
            acc[t] = fmaf(q.x, (float)((plo >> t)        & 1u), acc[t]);
            acc[t] = fmaf(q.y, (float)((plo >> (t + 16)) & 1u), acc[t]);
            acc[t] = fmaf(q.z, (float)((phi >> t)        & 1u), acc[t]);
            acc[t] = fmaf(q.w, (float)((phi >> (t + 16)) & 1u), acc[t]);
        }
    }
#pragma unroll
    for (int t = 0; t < T_STEPS; ++t)
        for (int o = 32; o; o >>= 1) acc[t] += __shfl_down(acc[t], o, 64);
    if (lane == 0) {
#pragma unroll
        for (int t = 0; t < T_STEPS; ++t) sred[wv][t] = acc[t];
    }
    __syncthreads();
    if (tid < T_STEPS) {
        float v = sred[0][tid] + sred[1][tid] + sred[2][tid] + sred[3][tid];
        base[(size_t)j * 16 + tid] = v;
    }
}

// ---------------- tiny sequential recursion: one lane per row ----------------
__global__ __launch_bounds__(64) void rec_kernel(
        const float* __restrict__ base, const int* __restrict__ ovl,
        const float* __restrict__ K, unsigned* __restrict__ mask_out,
        float* __restrict__ outp, int out_stride) {
    __shared__ float KO[256];                     // KO[t*16+r] = K[t][r] * OVL[r][t]
    const int tid = threadIdx.x;
    for (int p = tid; p < 256; p += 64) {
        const int t = p >> 4, r = p & 15;
        KO[p] = K[p] * (float)ovl[r * 16 + t];
    }
    __syncthreads();

    const int j = blockIdx.x * 64 + tid;
    float br[T_STEPS];
#pragma unroll
    for (int t = 0; t < T_STEPS; ++t) br[t] = base[(size_t)j * 16 + t];

    float vmem = 0.f;
    unsigned am = 0;
#pragma unroll
    for (int t = 0; t < T_STEPS; ++t) {
        float I = br[t];
        for (int r = 0; r < t; ++r)
            if ((am >> r) & 1u) I += KO[t * 16 + r];
        vmem = vmem * 0.95f + I * 0.1f;
        const bool s = vmem > 1.0f;
        if (s) { vmem = 0.f; am |= (1u << t); }
        if (outp) outp[t * out_stride + j] = s ? 1.0f : 0.0f;
    }
    mask_out[j] = am;
}

extern "C" void kernel_launch(void* const* d_in, const int* in_sizes, int n_in,
                              void* d_out, int out_size, void* d_ws, size_t ws_size,
                              hipStream_t stream) {
    const float* x     = (const float*)d_in[0];   // [16, 4096]
    const float* noise = (const float*)d_in[1];   // [16, 8192]
    const float* dop   = (const float*)d_in[2];   // [16]
    const float* W_enc = (const float*)d_in[3];   // [8192, 4096]
    const float* b_enc = (const float*)d_in[4];   // [8192]
    const float* W_va  = (const float*)d_in[5];   // [4096, 8192]
    const float* W_am  = (const float*)d_in[6];   // [1024, 4096]
    float* out = (float*)d_out;                   // [16, 1024] f32
    (void)in_sizes; (void)n_in; (void)out_size; (void)ws_size;

    char* ws = (char*)d_ws;
    size_t off = 0;
    unsigned* vmask  = (unsigned*)(ws + off); off += N_VIS * 4;
    unsigned* amask  = (unsigned*)(ws + off); off += N_ASSOC * 4;
    unsigned* mmask  = (unsigned*)(ws + off); off += N_MOTOR * 4;
    float*    K      = (float*)(ws + off);    off += 256 * 4;
    int*      ovl_v  = (int*)(ws + off);      off += 256 * 4;
    int*      ovl_a  = (int*)(ws + off);      off += 256 * 4;
    float*    baseVA = (float*)(ws + off);    off += (size_t)N_ASSOC * 16 * 4;
    float*    baseAM = (float*)(ws + off);    off += (size_t)N_MOTOR * 16 * 4;

    hipMemsetAsync(ovl_v, 0, 2 * 256 * 4, stream);   // ovl_v and ovl_a are adjacent

    ktab_kernel<<<1, 256, 0, stream>>>(dop, K);
    encoder_kernel<<<N_VIS / 8, 512, 0, stream>>>(x, noise, W_enc, b_enc, vmask);
    ovl_kernel<<<32, 256, 0, stream>>>(vmask, N_VIS / 32, ovl_v);
    base_kernel<8><<<N_ASSOC, 256, 0, stream>>>(W_va, vmask, baseVA);
    rec_kernel<<<N_ASSOC / 64, 64, 0, stream>>>(baseVA, ovl_v, K, amask, nullptr, 0);
    ovl_kernel<<<16, 256, 0, stream>>>(amask, N_ASSOC / 16, ovl_a);
    base_kernel<4><<<N_MOTOR, 256, 0, stream>>>(W_am, amask, baseAM);
    rec_kernel<<<N_MOTOR / 64, 64, 0, stream>>>(baseAM, ovl_a, K, mmask, out, N_MOTOR);
}